// Round 3
// baseline (176.245 us; speedup 1.0000x reference)
//
#include <hip/hip_runtime.h>

typedef unsigned short u16;
typedef __attribute__((ext_vector_type(8))) short frag8;   // 8 bf16 (4 VGPRs)
typedef __attribute__((ext_vector_type(4))) float f32x4;   // MFMA accumulator

__device__ __forceinline__ u16 f2bf(float f) {
  unsigned u; __builtin_memcpy(&u, &f, 4);
  u = (u + 0x7FFFu + ((u >> 16) & 1u)) >> 16;   // RNE (== v_cvt_pk_bf16_f32)
  return (u16)u;
}

// ---------------------------------------------------------------------------
// Round-9: per-wave-tile rewrite. Rounds 7/8 falsified occupancy and barrier-
// drain theories; wall/tile (~37k cyc) is 12x static cost (~3k) with ALL pipes
// <20% busy -> the 5-barrier lockstep structure itself is the bottleneck.
// New structure: wave = tile (lane = patch), ZERO per-tile barriers.
//   - DCT fully in registers from per-lane pixel loads (lanes span 2KB/row).
//   - feats/h relayout via per-wave LDS scratch (wave-local lgkmcnt only).
//   - weights staged once per block (ONE __syncthreads, amortized over 4 tiles):
//     w1S  [16 nt][64 lane] prebuilt frag8s (lane-linear, conflict-free)
//     w2tS [64 e][256 k] bf16, XOR-swizzled byte^=((e&7)<<4)  (2-way = free)
//   - hW per-wave [64 p][32 n] bf16, XOR-swizzled byte^=((p&3)<<4)
//   - GEMM1->GEMM2 pipelined per K-chunk of 32; emb acc in 64 VGPRs;
//     epilogue stores accs DIRECT to global (lane's 4 regs = contiguous float4,
//     16x64B segments per store instr = minimal line count). No embS.
// Fragment math identical to the proven kernel (same mfma shapes, same b1/relu/
// RNE path, same accumulation order) -> absmax should be unchanged (0.015625).
// ---------------------------------------------------------------------------

#define W2T_OFF   0        // 32768 B
#define W1S_OFF   32768    // 16384 B
#define B1S_OFF   49152    // 1024 B
#define FEATW_OFF 50176    // 4 * 2048 B  per-wave [64 p][16] bf16
#define HW_OFF    58368    // 4 * 4096 B  per-wave [64 p][32] bf16, swizzled
#define SMEM_BYTES 74752   // 2 blocks/CU (149.5 KB of 160 KB)

#define GRID 512           // 512 blocks * 4 waves = 2048 tiles, 1 tile/wave

__global__ __launch_bounds__(256, 2)
void dct_mlp_fused(const float* __restrict__ x,
                   const float* __restrict__ W1, const float* __restrict__ b1,
                   const float* __restrict__ W2, const float* __restrict__ b2,
                   float* __restrict__ out) {
  __shared__ __align__(16) char smem[SMEM_BYTES];

  const int t    = threadIdx.x;
  const int w    = t >> 6;
  const int lane = t & 63;          // lane == patch index within the tile
  const int quad = lane >> 4;
  const int l16  = lane & 15;

  const int tile = blockIdx.x * 4 + w;   // consecutive gy rows per block (L2)
  const int gy   = tile & 63;
  const int b    = tile >> 6;

  // ======== Block-wide weight staging (once, amortized over 4 tiles) ========
  ((float*)(smem + B1S_OFF))[t] = b1[t];

  // w1S: prebuilt A-fragments, [nt][lane] -> 16B each (lane-linear reads)
  {
    u16 zero = 0; (void)zero;
    #pragma unroll
    for (int nt2 = 0; nt2 < 4; ++nt2) {
      const int nt = w * 4 + nt2;
      frag8 f;
      #pragma unroll
      for (int j = 0; j < 8; ++j) {
        const int k = quad * 8 + j;
        f[j] = (k < 16) ? (short)f2bf(W1[k * 256 + nt * 16 + l16]) : (short)0;
      }
      *(frag8*)(smem + W1S_OFF + nt * 1024 + lane * 16) = f;
    }
  }
  // w2tS: W2 transposed to [e][k] bf16 with XOR swizzle (read = 2-way, free)
  {
    const int kq = t >> 4;            // 0..15
    const int e4 = (t & 15) * 4;      // 0..60
    #pragma unroll
    for (int it = 0; it < 16; ++it) {
      const int k = it * 16 + kq;
      float4 v = *(const float4*)(W2 + k * 64 + e4);
      #pragma unroll
      for (int j = 0; j < 4; ++j) {
        const int e = e4 + j;
        const float vj = j == 0 ? v.x : (j == 1 ? v.y : (j == 2 ? v.z : v.w));
        *(u16*)(smem + W2T_OFF + ((e * 512 + k * 2) ^ ((e & 7) << 4))) = f2bf(vj);
      }
    }
  }
  float b2e[4];
  #pragma unroll
  for (int et = 0; et < 4; ++et) b2e[et] = b2[et * 16 + l16];

  // ======== DCT: register-only, lane = patch (no LDS, no barrier) ========
  const float D4[4][8] = {
    { 0.35355339f, 0.35355339f, 0.35355339f, 0.35355339f,
      0.35355339f, 0.35355339f, 0.35355339f, 0.35355339f},
    { 0.49039264f, 0.41573481f, 0.27778512f, 0.09754516f,
     -0.09754516f,-0.27778512f,-0.41573481f,-0.49039264f},
    { 0.46193977f, 0.19134172f,-0.19134172f,-0.46193977f,
     -0.46193977f,-0.19134172f, 0.19134172f, 0.46193977f},
    { 0.41573481f,-0.09754516f,-0.49039264f,-0.27778512f,
      0.27778512f, 0.49039264f, 0.09754516f,-0.41573481f}
  };

  float tmp[4][8];
  #pragma unroll
  for (int kr = 0; kr < 4; ++kr)
    #pragma unroll
    for (int c = 0; c < 8; ++c) tmp[kr][c] = 0.f;

  const float* px = x + (size_t)(b * 3) * 262144 + (size_t)gy * 4096 + lane * 8;
  #pragma unroll
  for (int i = 0; i < 8; ++i) {
    const float* row = px + i * 512;
    float4 r0 = ((const float4*)row)[0];
    float4 r1 = ((const float4*)row)[1];
    float4 g0 = ((const float4*)(row + 262144))[0];
    float4 g1v = ((const float4*)(row + 262144))[1];
    float4 c0 = ((const float4*)(row + 524288))[0];
    float4 c1 = ((const float4*)(row + 524288))[1];
    float gr[8];
    gr[0] = 0.299f * r0.x + 0.587f * g0.x + 0.114f * c0.x;
    gr[1] = 0.299f * r0.y + 0.587f * g0.y + 0.114f * c0.y;
    gr[2] = 0.299f * r0.z + 0.587f * g0.z + 0.114f * c0.z;
    gr[3] = 0.299f * r0.w + 0.587f * g0.w + 0.114f * c0.w;
    gr[4] = 0.299f * r1.x + 0.587f * g1v.x + 0.114f * c1.x;
    gr[5] = 0.299f * r1.y + 0.587f * g1v.y + 0.114f * c1.y;
    gr[6] = 0.299f * r1.z + 0.587f * g1v.z + 0.114f * c1.z;
    gr[7] = 0.299f * r1.w + 0.587f * g1v.w + 0.114f * c1.w;
    #pragma unroll
    for (int kr = 0; kr < 4; ++kr)
      #pragma unroll
      for (int c = 0; c < 8; ++c)
        tmp[kr][c] = fmaf(D4[kr][i], gr[c], tmp[kr][c]);
  }

  // col pass + write feats (16 coeffs) to per-wave LDS scratch
  char* featWw = smem + FEATW_OFF + w * 2048;
  #pragma unroll
  for (int kr = 0; kr < 4; ++kr) {
    float cc[4] = {0.f, 0.f, 0.f, 0.f};
    #pragma unroll
    for (int l = 0; l < 4; ++l)
      #pragma unroll
      for (int j = 0; j < 8; ++j)
        cc[l] = fmaf(tmp[kr][j], D4[l][j], cc[l]);
    ushort4 fv;
    fv.x = f2bf(cc[0]); fv.y = f2bf(cc[1]); fv.z = f2bf(cc[2]); fv.w = f2bf(cc[3]);
    *(ushort4*)(featWw + lane * 32 + kr * 8) = fv;
  }

  __syncthreads();   // the ONLY barrier: weight staging visible to all waves

  // ======== per-wave MLP: GEMM1 -> hW -> GEMM2, K-chunks of 32 ========
  char*  w1Sp = smem + W1S_OFF;
  float* b1Sp = (float*)(smem + B1S_OFF);
  char*  w2tp = smem + W2T_OFF;
  char*  hWw  = smem + HW_OFF + w * 4096;

  // feats B-fragments (kc-invariant): B[k=quad*8+j][p=l16], k>=16 zero
  frag8 fB[4];
  #pragma unroll
  for (int pt = 0; pt < 4; ++pt) {
    frag8 z = {0,0,0,0,0,0,0,0};
    if (quad < 2)
      z = *(const frag8*)(featWw + (pt * 16 + l16) * 32 + quad * 16);
    fB[pt] = z;
  }

  f32x4 accs[4][4];
  #pragma unroll
  for (int pt = 0; pt < 4; ++pt)
    #pragma unroll
    for (int et = 0; et < 4; ++et) {
      f32x4 a = {b2e[et], b2e[et], b2e[et], b2e[et]};
      accs[pt][et] = a;
    }

  const unsigned hswz = (unsigned)((l16 & 3) << 4);   // p&3 == l16&3

  #pragma unroll
  for (int kc = 0; kc < 8; ++kc) {
    // ---- GEMM1: h chunk (32 hidden) = W1^T @ feats^T + b1, relu ----
    frag8 a0 = *(const frag8*)(w1Sp + (2 * kc) * 1024 + lane * 16);
    frag8 a1 = *(const frag8*)(w1Sp + (2 * kc + 1) * 1024 + lane * 16);
    f32x4 g1[2][4];
    #pragma unroll
    for (int ntl = 0; ntl < 2; ++ntl) {
      float4 bb = *(const float4*)(b1Sp + kc * 32 + ntl * 16 + quad * 4);
      #pragma unroll
      for (int pt = 0; pt < 4; ++pt) {
        f32x4 ac = {bb.x, bb.y, bb.z, bb.w};
        g1[ntl][pt] = __builtin_amdgcn_mfma_f32_16x16x32_bf16(
            ntl ? a1 : a0, fB[pt], ac, 0, 0, 0);
      }
    }
    // relu + pack -> per-wave hW (swizzled)
    #pragma unroll
    for (int pt = 0; pt < 4; ++pt) {
      const unsigned rb = (unsigned)((pt * 16 + l16) * 64);
      #pragma unroll
      for (int ntl = 0; ntl < 2; ++ntl) {
        f32x4 v = g1[ntl][pt];
        float m0 = fmaxf(v[0], 0.f), m1 = fmaxf(v[1], 0.f);
        float m2 = fmaxf(v[2], 0.f), m3 = fmaxf(v[3], 0.f);
        unsigned d0, d1;
        asm("v_cvt_pk_bf16_f32 %0, %1, %2" : "=v"(d0) : "v"(m0), "v"(m1));
        asm("v_cvt_pk_bf16_f32 %0, %1, %2" : "=v"(d1) : "v"(m2), "v"(m3));
        uint2 dd; dd.x = d0; dd.y = d1;
        *(uint2*)(hWw + ((rb + ntl * 32 + quad * 8) ^ hswz)) = dd;
      }
    }
    // ---- GEMM2: emb += h_chunk @ W2[kc*32 .. kc*32+31][:] ----
    frag8 w2b[4];
    #pragma unroll
    for (int et = 0; et < 4; ++et) {
      const int e = et * 16 + l16;
      w2b[et] = *(const frag8*)(w2tp +
                  ((e * 512 + kc * 64 + quad * 16) ^ ((e & 7) << 4)));
    }
    frag8 hA[4];
    #pragma unroll
    for (int pt = 0; pt < 4; ++pt) {
      const unsigned rb = (unsigned)((pt * 16 + l16) * 64);
      hA[pt] = *(const frag8*)(hWw + ((rb + quad * 16) ^ hswz));
    }
    #pragma unroll
    for (int pt = 0; pt < 4; ++pt)
      #pragma unroll
      for (int et = 0; et < 4; ++et)
        accs[pt][et] = __builtin_amdgcn_mfma_f32_16x16x32_bf16(
            hA[pt], w2b[et], accs[pt][et], 0, 0, 0);
  }

  // ======== Epilogue: direct store (lane regs j=0..3 are contiguous p) ======
  #pragma unroll
  for (int pt = 0; pt < 4; ++pt)
    #pragma unroll
    for (int et = 0; et < 4; ++et) {
      f32x4 v = accs[pt][et];
      float4 o; o.x = v[0]; o.y = v[1]; o.z = v[2]; o.w = v[3];
      float* dst = out + (((size_t)b * 64 + et * 16 + l16) * 64 + gy) * 64
                       + pt * 16 + quad * 4;
      *(float4*)dst = o;
    }
}

extern "C" void kernel_launch(void* const* d_in, const int* in_sizes, int n_in,
                              void* d_out, int out_size, void* d_ws, size_t ws_size,
                              hipStream_t stream) {
  const float* x  = (const float*)d_in[0];
  const float* W1 = (const float*)d_in[1];
  const float* b1 = (const float*)d_in[2];
  const float* W2 = (const float*)d_in[3];
  const float* b2 = (const float*)d_in[4];
  float* out = (float*)d_out;
  dct_mlp_fused<<<dim3(GRID, 1, 1), dim3(256, 1, 1), 0, stream>>>(x, W1, b1, W2, b2, out);
}

// Round 4
// 172.838 us; speedup vs baseline: 1.0197x; 1.0197x over previous
//
#include <hip/hip_runtime.h>

typedef unsigned short u16;
typedef __attribute__((ext_vector_type(8))) short frag8;   // 8 bf16 (4 VGPRs)
typedef __attribute__((ext_vector_type(4))) float f32x4;   // MFMA accumulator

__device__ __forceinline__ u16 f2bf(float f) {
  unsigned u; __builtin_memcpy(&u, &f, 4);
  u = (u + 0x7FFFu + ((u >> 16) & 1u)) >> 16;   // RNE (== v_cvt_pk_bf16_f32)
  return (u16)u;
}

// ---------------------------------------------------------------------------
// Round-10: kill the per-block weight-staging prologue.
// Evidence: rounds 7-9 falsified occupancy / barrier-drain / lockstep; all
// structures pinned at ~63 us with every pipe <17% busy. The shared invariant
// was ~96 scalar global weight loads + f2bf per thread per block before any
// work. Round-7's 2x block count cost +29 us -> ~14.5 us FIXED cost per block
// (staging), ~4.3 us per tile. Fix: a tiny prep kernel (same stream, ordered;
// kernel-boundary L2 writeback/invalidate makes stores visible cross-XCD)
// prebuilds bf16 MFMA fragments in the workspace:
//   w1f: frag8 per (nt in 0..15, lane)        @ ws+0      (16 KB)
//   w2f: frag8 per (kc*4+et in 0..31, lane)   @ ws+16384  (32 KB)
// A wave's fragment load becomes ONE coalesced global_load_dwordx4 (1 KB/instr,
// L2-hot). Main kernel: 2048 single-wave blocks (wave = tile), ZERO barriers,
// no weight LDS; LDS = 6 KB/block (featW 2K + hW 4K) -> 8 blocks/CU.
// Fragment contents byte-identical to round-9 (same mfma order, b1 seeding,
// relu/RNE, epilogue) -> absmax expected unchanged (0.015625).
// ---------------------------------------------------------------------------

#define FEATW_OFF 0       // 2048 B  [64 p][16 coeff] bf16
#define HW_OFF    2048    // 4096 B  [64 p][32 n] bf16, XOR-swizzled
#define SMEM_BYTES 6144

__global__ __launch_bounds__(256)
void prep_weights(const float* __restrict__ W1, const float* __restrict__ W2,
                  u16* __restrict__ wf) {
  const int g    = blockIdx.x * 256 + threadIdx.x;   // 0..3071
  const int lane = g & 63;
  const int quad = (g >> 4) & 3;
  const int l16  = g & 15;
  frag8 f;
  if (g < 1024) {
    // w1f[nt][lane]: A-frag of W1^T, f[j] = W1[k=quad*8+j][nt*16+l16], k>=16 -> 0
    const int nt = g >> 6;
    #pragma unroll
    for (int j = 0; j < 8; ++j) {
      const int k = quad * 8 + j;
      f[j] = (k < 16) ? (short)f2bf(W1[k * 256 + nt * 16 + l16]) : (short)0;
    }
    *(frag8*)(wf + (size_t)g * 8) = f;
  } else {
    // w2f[kc*4+et][lane]: B-frag, f[j] = W2[kc*32+quad*8+j][et*16+l16]
    const int idx = g - 1024;                        // 0..2047
    const int kc  = idx >> 8;
    const int et  = (idx >> 6) & 3;
    #pragma unroll
    for (int j = 0; j < 8; ++j)
      f[j] = (short)f2bf(W2[(kc * 32 + quad * 8 + j) * 64 + et * 16 + l16]);
    *(frag8*)(wf + 8192 + (size_t)idx * 8) = f;
  }
}

__global__ __launch_bounds__(64, 2)   // 1 wave/block; 8 blocks/CU resident
void dct_mlp_fused(const float* __restrict__ x,
                   const u16* __restrict__ wf,
                   const float* __restrict__ b1,
                   const float* __restrict__ b2,
                   float* __restrict__ out) {
  __shared__ __align__(16) char smem[SMEM_BYTES];

  const int lane = threadIdx.x;     // lane == patch index within the tile
  const int quad = lane >> 4;
  const int l16  = lane & 15;

  const int tile = blockIdx.x;      // 0..2047
  const int gy   = tile & 63;
  const int b    = tile >> 6;

  // ======== DCT: register-only, lane = patch ========
  const float D4[4][8] = {
    { 0.35355339f, 0.35355339f, 0.35355339f, 0.35355339f,
      0.35355339f, 0.35355339f, 0.35355339f, 0.35355339f},
    { 0.49039264f, 0.41573481f, 0.27778512f, 0.09754516f,
     -0.09754516f,-0.27778512f,-0.41573481f,-0.49039264f},
    { 0.46193977f, 0.19134172f,-0.19134172f,-0.46193977f,
     -0.46193977f,-0.19134172f, 0.19134172f, 0.46193977f},
    { 0.41573481f,-0.09754516f,-0.49039264f,-0.27778512f,
      0.27778512f, 0.49039264f, 0.09754516f,-0.41573481f}
  };

  float tmp[4][8];
  #pragma unroll
  for (int kr = 0; kr < 4; ++kr)
    #pragma unroll
    for (int c = 0; c < 8; ++c) tmp[kr][c] = 0.f;

  const float* px = x + (size_t)(b * 3) * 262144 + (size_t)gy * 4096 + lane * 8;
  #pragma unroll
  for (int i = 0; i < 8; ++i) {
    const float* row = px + i * 512;
    float4 r0 = ((const float4*)row)[0];
    float4 r1 = ((const float4*)row)[1];
    float4 g0 = ((const float4*)(row + 262144))[0];
    float4 g1v = ((const float4*)(row + 262144))[1];
    float4 c0 = ((const float4*)(row + 524288))[0];
    float4 c1 = ((const float4*)(row + 524288))[1];
    float gr[8];
    gr[0] = 0.299f * r0.x + 0.587f * g0.x + 0.114f * c0.x;
    gr[1] = 0.299f * r0.y + 0.587f * g0.y + 0.114f * c0.y;
    gr[2] = 0.299f * r0.z + 0.587f * g0.z + 0.114f * c0.z;
    gr[3] = 0.299f * r0.w + 0.587f * g0.w + 0.114f * c0.w;
    gr[4] = 0.299f * r1.x + 0.587f * g1v.x + 0.114f * c1.x;
    gr[5] = 0.299f * r1.y + 0.587f * g1v.y + 0.114f * c1.y;
    gr[6] = 0.299f * r1.z + 0.587f * g1v.z + 0.114f * c1.z;
    gr[7] = 0.299f * r1.w + 0.587f * g1v.w + 0.114f * c1.w;
    #pragma unroll
    for (int kr = 0; kr < 4; ++kr)
      #pragma unroll
      for (int c = 0; c < 8; ++c)
        tmp[kr][c] = fmaf(D4[kr][i], gr[c], tmp[kr][c]);
  }

  // col pass + write feats (16 coeffs) to per-block LDS scratch
  char* featWw = smem + FEATW_OFF;
  #pragma unroll
  for (int kr = 0; kr < 4; ++kr) {
    float cc[4] = {0.f, 0.f, 0.f, 0.f};
    #pragma unroll
    for (int l = 0; l < 4; ++l)
      #pragma unroll
      for (int j = 0; j < 8; ++j)
        cc[l] = fmaf(tmp[kr][j], D4[l][j], cc[l]);
    ushort4 fv;
    fv.x = f2bf(cc[0]); fv.y = f2bf(cc[1]); fv.z = f2bf(cc[2]); fv.w = f2bf(cc[3]);
    *(ushort4*)(featWw + lane * 32 + kr * 8) = fv;
  }

  // feats B-fragments (kc-invariant): B[k=quad*8+j][p=l16], k>=16 zero.
  // Wave-local LDS round-trip; compiler-inserted lgkmcnt, no barrier needed.
  frag8 fB[4];
  #pragma unroll
  for (int pt = 0; pt < 4; ++pt) {
    frag8 z = {0,0,0,0,0,0,0,0};
    if (quad < 2)
      z = *(const frag8*)(featWw + (pt * 16 + l16) * 32 + quad * 16);
    fB[pt] = z;
  }

  float b2e[4];
  #pragma unroll
  for (int et = 0; et < 4; ++et) b2e[et] = b2[et * 16 + l16];

  f32x4 accs[4][4];
  #pragma unroll
  for (int pt = 0; pt < 4; ++pt)
    #pragma unroll
    for (int et = 0; et < 4; ++et) {
      f32x4 a = {b2e[et], b2e[et], b2e[et], b2e[et]};
      accs[pt][et] = a;
    }

  char* hWw = smem + HW_OFF;
  const unsigned hswz = (unsigned)((l16 & 3) << 4);   // p&3 == l16&3

  const u16* w1f = wf;          // frag8 per (nt, lane): nt*512 + lane*8 u16
  const u16* w2f = wf + 8192;   // frag8 per (kc*4+et, lane)

  #pragma unroll
  for (int kc = 0; kc < 8; ++kc) {
    // ---- weight fragments: one coalesced dwordx4 per frag, L2-hot ----
    frag8 a0 = *(const frag8*)(w1f + (size_t)(2 * kc) * 512 + lane * 8);
    frag8 a1 = *(const frag8*)(w1f + (size_t)(2 * kc + 1) * 512 + lane * 8);
    frag8 w2b[4];
    #pragma unroll
    for (int et = 0; et < 4; ++et)
      w2b[et] = *(const frag8*)(w2f + (size_t)(kc * 4 + et) * 512 + lane * 8);

    // ---- GEMM1: h chunk (32 hidden) = W1^T @ feats^T + b1, relu ----
    f32x4 g1[2][4];
    #pragma unroll
    for (int ntl = 0; ntl < 2; ++ntl) {
      float4 bb = *(const float4*)(b1 + kc * 32 + ntl * 16 + quad * 4);
      #pragma unroll
      for (int pt = 0; pt < 4; ++pt) {
        f32x4 ac = {bb.x, bb.y, bb.z, bb.w};
        g1[ntl][pt] = __builtin_amdgcn_mfma_f32_16x16x32_bf16(
            ntl ? a1 : a0, fB[pt], ac, 0, 0, 0);
      }
    }
    // relu + pack -> hW (swizzled)
    #pragma unroll
    for (int pt = 0; pt < 4; ++pt) {
      const unsigned rb = (unsigned)((pt * 16 + l16) * 64);
      #pragma unroll
      for (int ntl = 0; ntl < 2; ++ntl) {
        f32x4 v = g1[ntl][pt];
        float m0 = fmaxf(v[0], 0.f), m1 = fmaxf(v[1], 0.f);
        float m2 = fmaxf(v[2], 0.f), m3 = fmaxf(v[3], 0.f);
        unsigned d0, d1;
        asm("v_cvt_pk_bf16_f32 %0, %1, %2" : "=v"(d0) : "v"(m0), "v"(m1));
        asm("v_cvt_pk_bf16_f32 %0, %1, %2" : "=v"(d1) : "v"(m2), "v"(m3));
        uint2 dd; dd.x = d0; dd.y = d1;
        *(uint2*)(hWw + ((rb + ntl * 32 + quad * 8) ^ hswz)) = dd;
      }
    }
    // ---- GEMM2: emb += h_chunk @ W2[kc*32 .. kc*32+31][:] ----
    frag8 hA[4];
    #pragma unroll
    for (int pt = 0; pt < 4; ++pt) {
      const unsigned rb = (unsigned)((pt * 16 + l16) * 64);
      hA[pt] = *(const frag8*)(hWw + ((rb + quad * 16) ^ hswz));
    }
    #pragma unroll
    for (int pt = 0; pt < 4; ++pt)
      #pragma unroll
      for (int et = 0; et < 4; ++et)
        accs[pt][et] = __builtin_amdgcn_mfma_f32_16x16x32_bf16(
            hA[pt], w2b[et], accs[pt][et], 0, 0, 0);
  }

  // ======== Epilogue: direct store (lane regs j=0..3 are contiguous p) ======
  #pragma unroll
  for (int pt = 0; pt < 4; ++pt)
    #pragma unroll
    for (int et = 0; et < 4; ++et) {
      f32x4 v = accs[pt][et];
      float4 o; o.x = v[0]; o.y = v[1]; o.z = v[2]; o.w = v[3];
      float* dst = out + (((size_t)b * 64 + et * 16 + l16) * 64 + gy) * 64
                       + pt * 16 + quad * 4;
      *(float4*)dst = o;
    }
}

extern "C" void kernel_launch(void* const* d_in, const int* in_sizes, int n_in,
                              void* d_out, int out_size, void* d_ws, size_t ws_size,
                              hipStream_t stream) {
  const float* x  = (const float*)d_in[0];
  const float* W1 = (const float*)d_in[1];
  const float* b1 = (const float*)d_in[2];
  const float* W2 = (const float*)d_in[3];
  const float* b2 = (const float*)d_in[4];
  float* out = (float*)d_out;
  u16* wf = (u16*)d_ws;   // needs 48 KB of workspace

  prep_weights<<<dim3(12, 1, 1), dim3(256, 1, 1), 0, stream>>>(W1, W2, wf);
  dct_mlp_fused<<<dim3(2048, 1, 1), dim3(64, 1, 1), 0, stream>>>(x, wf, b1, b2, out);
}